// Round 8
// baseline (104.010 us; speedup 1.0000x reference)
//
#include <hip/hip_runtime.h>
#include <cstdint>

typedef unsigned int u32;
typedef unsigned short u16;
typedef unsigned long long u64;
typedef __attribute__((ext_vector_type(4))) float f32x4;
typedef __attribute__((ext_vector_type(8))) short s16x8;

#define D_IN   784
#define D_H    2048
#define D_O    10
#define T_STEPS 100
#define KB1    25          // ceil(784/32) k-blocks for layer-1 GEMM

static __device__ __forceinline__ u16 f2bf_rn(float f) {
  u32 u = __float_as_uint(f);
  u32 r = u + 0x7FFFu + ((u >> 16) & 1u);
  return (u16)(r >> 16);
}
static __device__ __forceinline__ float bf2f(u16 h) {
  return __uint_as_float(((u32)h) << 16);
}

// ---------------------------------------------------------------------------
// K0a: W2 (f32) -> bf16 hi/lo MFMA B-fragments (round-1/3 verbatim, verified).
// ---------------------------------------------------------------------------
__global__ __launch_bounds__(256) void k_prep_w2(const float* __restrict__ W2,
                                                 u32* __restrict__ Phi,
                                                 u32* __restrict__ Plo) {
  int t = blockIdx.x * 256 + threadIdx.x;
  if (t >= 64 * 64) return;
  int kb = t >> 6, l = t & 63;
  int o = l & 15;
  int kbase = kb * 32 + ((l >> 4) << 3);
  u32 hw[4], lw[4];
#pragma unroll
  for (int p = 0; p < 4; ++p) {
    u32 hp = 0, lp = 0;
#pragma unroll
    for (int q = 0; q < 2; ++q) {
      float f = (o < D_O) ? W2[o * D_H + kbase + 2 * p + q] : 0.0f;
      u16 h = f2bf_rn(f);
      float rr = __fsub_rn(f, bf2f(h));
      u16 lo = f2bf_rn(rr);
      hp |= ((u32)h) << (16 * q);
      lp |= ((u32)lo) << (16 * q);
    }
    hw[p] = hp; lw[p] = lp;
  }
  int base = (kb * 64 + l) * 4;
#pragma unroll
  for (int p = 0; p < 4; ++p) { Phi[base + p] = hw[p]; Plo[base + p] = lw[p]; }
}

// ---------------------------------------------------------------------------
// K0b: triple-split x and W1 into bf16 MFMA fragments (round-3 verbatim).
// ---------------------------------------------------------------------------
__global__ __launch_bounds__(256) void k_split(const float* __restrict__ x,
                                               const float* __restrict__ W1,
                                               uint4* __restrict__ Xs,
                                               uint4* __restrict__ Ws) {
  int t = blockIdx.x * 256 + threadIdx.x;
  const int XT = KB1 * 32 * 64;     // 51200
  const int WT = KB1 * 128 * 64;    // 204800
  if (t >= XT + WT) return;
  const float* base; uint4* dst; int kb, l, frag, nfr;
  if (t < XT) {
    l = t & 63; int f = t >> 6; frag = f & 31; kb = f >> 5;
    base = x; dst = Xs; nfr = 32;
  } else {
    int t2 = t - XT;
    l = t2 & 63; int f = t2 >> 6; frag = f & 127; kb = f >> 7;
    base = W1; dst = Ws; nfr = 128;
  }
  int row = frag * 16 + (l & 15);
  int ks = kb * 32 + ((l >> 4) << 3);
  const float* rp = base + (size_t)row * D_IN;
  float e[8];
#pragma unroll
  for (int q = 0; q < 8; ++q) e[q] = (ks + q < D_IN) ? rp[ks + q] : 0.0f;
  u32 w0[4], w1[4], w2[4];
#pragma unroll
  for (int p = 0; p < 4; ++p) {
    u32 a0 = 0, a1 = 0, a2 = 0;
#pragma unroll
    for (int q = 0; q < 2; ++q) {
      float v = e[2 * p + q];
      u16 s0 = f2bf_rn(v); float r1 = __fsub_rn(v, bf2f(s0));
      u16 s1 = f2bf_rn(r1); float r2 = __fsub_rn(r1, bf2f(s1));
      u16 s2 = f2bf_rn(r2);
      a0 |= ((u32)s0) << (16 * q);
      a1 |= ((u32)s1) << (16 * q);
      a2 |= ((u32)s2) << (16 * q);
    }
    w0[p] = a0; w1[p] = a1; w2[p] = a2;
  }
  size_t bi = ((size_t)kb * nfr + frag) * 64 + l;
  size_t ss = (size_t)KB1 * nfr * 64;
  dst[0 * ss + bi] = make_uint4(w0[0], w0[1], w0[2], w0[3]);
  dst[1 * ss + bi] = make_uint4(w1[0], w1[1], w1[2], w1[3]);
  dst[2 * ss + bi] = make_uint4(w2[0], w2[1], w2[2], w2[3]);
}

// ---------------------------------------------------------------------------
// K1: cur1 = x @ W1^T + b1 via 6-product bf16-triple MFMA (round-3 verbatim).
// ---------------------------------------------------------------------------
__global__ __launch_bounds__(512) void k_gemm1(const uint4* __restrict__ Xs,
                                               const uint4* __restrict__ Ws,
                                               const float* __restrict__ b1,
                                               float* __restrict__ cur1) {
  __shared__ float4 comb[16][64];   // 16 KB
  const int tid = threadIdx.x, wave = tid >> 6, lane = tid & 63;
  const int mb = blockIdx.y, nb = blockIdx.x;
  const int wn = wave & 3;
  const int nfrag = nb * 4 + wn;
  const size_t ssx = (size_t)KB1 * 32 * 64;
  const size_t ssw = (size_t)KB1 * 128 * 64;
  f32x4 acc[4] = {{0.f,0.f,0.f,0.f},{0.f,0.f,0.f,0.f},{0.f,0.f,0.f,0.f},{0.f,0.f,0.f,0.f}};
  for (int kb = (wave >> 2); kb < KB1; kb += 2) {
    const size_t bb = (size_t)kb * 8192 + (size_t)nfrag * 64 + lane;
    uint4 b0u = Ws[0 * ssw + bb];
    uint4 b1u = Ws[1 * ssw + bb];
    uint4 b2u = Ws[2 * ssw + bb];
    s16x8 B0 = __builtin_bit_cast(s16x8, b0u);
    s16x8 B1 = __builtin_bit_cast(s16x8, b1u);
    s16x8 B2 = __builtin_bit_cast(s16x8, b2u);
#pragma unroll
    for (int fm = 0; fm < 4; ++fm) {
      const size_t ab = (size_t)kb * 2048 + (size_t)(mb * 4 + fm) * 64 + lane;
      uint4 a0u = Xs[0 * ssx + ab];
      uint4 a1u = Xs[1 * ssx + ab];
      uint4 a2u = Xs[2 * ssx + ab];
      s16x8 A0 = __builtin_bit_cast(s16x8, a0u);
      s16x8 A1 = __builtin_bit_cast(s16x8, a1u);
      s16x8 A2 = __builtin_bit_cast(s16x8, a2u);
      acc[fm] = __builtin_amdgcn_mfma_f32_16x16x32_bf16(A0, B0, acc[fm], 0, 0, 0);
      acc[fm] = __builtin_amdgcn_mfma_f32_16x16x32_bf16(A0, B1, acc[fm], 0, 0, 0);
      acc[fm] = __builtin_amdgcn_mfma_f32_16x16x32_bf16(A1, B0, acc[fm], 0, 0, 0);
      acc[fm] = __builtin_amdgcn_mfma_f32_16x16x32_bf16(A1, B1, acc[fm], 0, 0, 0);
      acc[fm] = __builtin_amdgcn_mfma_f32_16x16x32_bf16(A0, B2, acc[fm], 0, 0, 0);
      acc[fm] = __builtin_amdgcn_mfma_f32_16x16x32_bf16(A2, B0, acc[fm], 0, 0, 0);
    }
  }
  if (wave >= 4) {
#pragma unroll
    for (int fm = 0; fm < 4; ++fm)
      comb[wn * 4 + fm][lane] = make_float4(acc[fm][0], acc[fm][1], acc[fm][2], acc[fm][3]);
  }
  __syncthreads();
  if (wave < 4) {
    const float bv = b1[nfrag * 16 + (lane & 15)];
    const int rbase = (lane >> 4) * 4, col = lane & 15;
#pragma unroll
    for (int fm = 0; fm < 4; ++fm) {
      float4 o = comb[wn * 4 + fm][lane];
      float v[4] = {acc[fm][0] + o.x, acc[fm][1] + o.y, acc[fm][2] + o.z, acc[fm][3] + o.w};
#pragma unroll
      for (int r = 0; r < 4; ++r) {
        int m = mb * 64 + fm * 16 + rbase + r;
        cur1[(size_t)m * D_H + nfrag * 16 + col] = v[r] + bv;
      }
    }
  }
}

// ---------------------------------------------------------------------------
// K2a: layer-1 recurrence at FULL occupancy. 2048 blocks x 256 thr; block =
// (b, quarter); 2 neurons/thread; no LDS, no barriers. Lane t captures step-t
// ballot via cndmask; coalesced 256B dumps to bits[b][h32][112].
// ---------------------------------------------------------------------------
__global__ __launch_bounds__(256) void k2a(const float* __restrict__ cur1,
                                           const float* __restrict__ beta1p,
                                           u32* __restrict__ bits) {
  const int blk = blockIdx.x;
  const int b = blk >> 2, q = blk & 3;
  const int tid = threadIdx.x;
  const int w = tid >> 6, lane = tid & 63;
  const float b1c = fminf(fmaxf(beta1p[0], 0.0f), 1.0f);
  float cv[2], memv[2]; bool sp[2]; u32 alo[2], ahi[2];
#pragma unroll
  for (int j = 0; j < 2; ++j) {
    cv[j] = cur1[(size_t)b * D_H + q * 512 + j * 256 + tid];
    memv[j] = 0.0f; sp[j] = false; alo[j] = 0u; ahi[j] = 0u;
  }
  for (int t = 0; t < 64; ++t) {
    const bool mine = (lane == t);
#pragma unroll
    for (int j = 0; j < 2; ++j) {
      float m = __fmul_rn(b1c, memv[j]);
      m = __fadd_rn(m, cv[j]);
      if (sp[j]) m = __fsub_rn(m, 1.0f);
      sp[j] = (m > 1.0f);
      memv[j] = m;
      u64 msk = __ballot(sp[j]);
      alo[j] = mine ? (u32)msk : alo[j];
      ahi[j] = mine ? (u32)(msk >> 32) : ahi[j];
    }
  }
#pragma unroll
  for (int j = 0; j < 2; ++j) {
    const int h32 = q * 16 + j * 8 + w * 2;
    size_t r0 = ((size_t)b * 64 + h32) * 112;
    bits[r0 + lane]       = alo[j];
    bits[r0 + 112 + lane] = ahi[j];
    alo[j] = 0u; ahi[j] = 0u;
  }
  for (int t = 64; t < T_STEPS; ++t) {
    const bool mine = (lane == t - 64);
#pragma unroll
    for (int j = 0; j < 2; ++j) {
      float m = __fmul_rn(b1c, memv[j]);
      m = __fadd_rn(m, cv[j]);
      if (sp[j]) m = __fsub_rn(m, 1.0f);
      sp[j] = (m > 1.0f);
      memv[j] = m;
      u64 msk = __ballot(sp[j]);
      alo[j] = mine ? (u32)msk : alo[j];
      ahi[j] = mine ? (u32)(msk >> 32) : ahi[j];
    }
  }
  if (lane < 48) {   // t = 64..111; lanes 36..47 carry zeros (pad rows)
#pragma unroll
    for (int j = 0; j < 2; ++j) {
      const int h32 = q * 16 + j * 8 + w * 2;
      size_t r0 = ((size_t)b * 64 + h32) * 112 + 64;
      bits[r0 + lane]       = alo[j];
      bits[r0 + 112 + lane] = ahi[j];
    }
  }
}

// ---------------------------------------------------------------------------
// K2b: cur2 MFMA only (R7-proven staging + expand), c2 -> global.
// ---------------------------------------------------------------------------
__global__ __launch_bounds__(512) void k2b(const u32* __restrict__ bits,
                                           const u32* __restrict__ Phi,
                                           const u32* __restrict__ Plo,
                                           float* __restrict__ c2g) {
  __shared__ uint4 PhiS[8][64];
  __shared__ uint4 PloS[8][64];
  const int b = blockIdx.x, tid = threadIdx.x;
  const int wave = tid >> 6, lane = tid & 63;
  f32x4 acc = {0.f, 0.f, 0.f, 0.f};
  const int trow = wave * 16 + (lane & 15);
  const int shift = (lane >> 4) * 8;
  const u32* brow = bits + (size_t)b * 64 * 112;
  for (int c = 0; c < 8; ++c) {
    PhiS[wave][lane] = *(const uint4*)(Phi + (size_t)((c * 8 + wave) * 64 + lane) * 4);
    PloS[wave][lane] = *(const uint4*)(Plo + (size_t)((c * 8 + wave) * 64 + lane) * 4);
    __syncthreads();
    if (wave < 7) {
#pragma unroll
      for (int kk = 0; kk < 8; ++kk) {
        u32 w8 = (brow[(c * 8 + kk) * 112 + trow] >> shift) & 0xFFu;
        u32 u = w8 | (w8 << 15);
        uint4 a0u;
        ((u32*)&a0u)[0] = ( u        & 0x00010001u) * 0x3F80u;
        ((u32*)&a0u)[1] = ((u >> 2)  & 0x00010001u) * 0x3F80u;
        ((u32*)&a0u)[2] = ((u >> 4)  & 0x00010001u) * 0x3F80u;
        ((u32*)&a0u)[3] = ((u >> 6)  & 0x00010001u) * 0x3F80u;
        s16x8 a   = __builtin_bit_cast(s16x8, a0u);
        s16x8 bhi = __builtin_bit_cast(s16x8, PhiS[kk][lane]);
        s16x8 blo = __builtin_bit_cast(s16x8, PloS[kk][lane]);
        acc = __builtin_amdgcn_mfma_f32_16x16x32_bf16(a, bhi, acc, 0, 0, 0);
        acc = __builtin_amdgcn_mfma_f32_16x16x32_bf16(a, blo, acc, 0, 0, 0);
      }
    }
    __syncthreads();
  }
  if (wave < 7) {
    const int colw = lane & 15, rbase = (lane >> 4) * 4;
#pragma unroll
    for (int r = 0; r < 4; ++r)
      c2g[((size_t)b * 112 + wave * 16 + rbase + r) * 16 + colw] = acc[r];
  }
}

// ---------------------------------------------------------------------------
// K2c: layer-2 recurrence + mean + softmax. 64 blocks x 128 thr; one (b)
// per 16-lane group, one o per lane.
// ---------------------------------------------------------------------------
__global__ __launch_bounds__(128) void k2c(const float* __restrict__ c2g,
                                           const float* __restrict__ b2,
                                           const float* __restrict__ beta2p,
                                           float* __restrict__ out) {
  const int tid = threadIdx.x;
  const int g = tid >> 4, o = tid & 15;
  const int b = blockIdx.x * 8 + g;
  const float b2c = fminf(fmaxf(beta2p[0], 0.0f), 1.0f);
  const bool valid = (o < D_O);
  const float bb = valid ? b2[o] : 0.0f;
  const float* crow = c2g + (size_t)b * 112 * 16;
  float m2 = 0.0f; bool s2 = false; int cnt = 0;
  for (int t0 = 0; t0 < T_STEPS; t0 += 10) {
    float cc[10];
#pragma unroll
    for (int i = 0; i < 10; ++i) cc[i] = crow[(t0 + i) * 16 + o];
#pragma unroll
    for (int i = 0; i < 10; ++i) {
      float cI = __fadd_rn(cc[i], bb);
      float m = __fadd_rn(__fmul_rn(b2c, m2), cI);
      if (s2) m = __fsub_rn(m, 1.0f);
      s2 = (m > 1.0f);
      m2 = m;
      cnt += s2 ? 1 : 0;
    }
  }
  float mean = valid ? ((float)cnt / 100.0f) : -1e30f;
  float mx = mean;
#pragma unroll
  for (int i = 8; i >= 1; i >>= 1) mx = fmaxf(mx, __shfl_xor(mx, i, 16));
  float e = valid ? expf(mean - mx) : 0.0f;
  float s = e;
#pragma unroll
  for (int i = 8; i >= 1; i >>= 1) s = __fadd_rn(s, __shfl_xor(s, i, 16));
  if (valid) out[(size_t)b * D_O + o] = e / s;
}

// ---------------------------------------------------------------------------
// Fallback fused temporal kernel (round-7 verbatim) for small ws_size.
// ---------------------------------------------------------------------------
__global__ __launch_bounds__(512) void k_snn2(const float* __restrict__ cur1,
                                              const u32* __restrict__ Phi,
                                              const u32* __restrict__ Plo,
                                              const float* __restrict__ b2,
                                              const float* __restrict__ beta1p,
                                              const float* __restrict__ beta2p,
                                              float* __restrict__ out) {
  __shared__ u32  bitsS[64][112];
  __shared__ uint4 PhiS[8][64];
  __shared__ uint4 PloS[8][64];
  __shared__ float c2[112][18];
  const int b = blockIdx.x, tid = threadIdx.x;
  const int wave = tid >> 6, lane = tid & 63;
  const float b1c = fminf(fmaxf(beta1p[0], 0.0f), 1.0f);
  const float b2c = fminf(fmaxf(beta2p[0], 0.0f), 1.0f);
  float cv[4], memv[4]; bool sp[4];
  u32 alo[4], ahi[4];
#pragma unroll
  for (int j = 0; j < 4; ++j) {
    cv[j] = cur1[(size_t)b * D_H + j * 512 + tid];
    memv[j] = 0.0f; sp[j] = false; alo[j] = 0u; ahi[j] = 0u;
  }
  for (int t = 0; t < 64; ++t) {
    const bool mine = (lane == t);
#pragma unroll
    for (int j = 0; j < 4; ++j) {
      float m = __fmul_rn(b1c, memv[j]);
      m = __fadd_rn(m, cv[j]);
      if (sp[j]) m = __fsub_rn(m, 1.0f);
      sp[j] = (m > 1.0f);
      memv[j] = m;
      u64 msk = __ballot(sp[j]);
      alo[j] = mine ? (u32)msk : alo[j];
      ahi[j] = mine ? (u32)(msk >> 32) : ahi[j];
    }
  }
#pragma unroll
  for (int j = 0; j < 4; ++j) {
    bitsS[j * 16 + wave * 2 + 0][lane] = alo[j];
    bitsS[j * 16 + wave * 2 + 1][lane] = ahi[j];
    alo[j] = 0u; ahi[j] = 0u;
  }
  for (int t = 64; t < T_STEPS; ++t) {
    const bool mine = (lane == t - 64);
#pragma unroll
    for (int j = 0; j < 4; ++j) {
      float m = __fmul_rn(b1c, memv[j]);
      m = __fadd_rn(m, cv[j]);
      if (sp[j]) m = __fsub_rn(m, 1.0f);
      sp[j] = (m > 1.0f);
      memv[j] = m;
      u64 msk = __ballot(sp[j]);
      alo[j] = mine ? (u32)msk : alo[j];
      ahi[j] = mine ? (u32)(msk >> 32) : ahi[j];
    }
  }
  if (lane < 48) {
#pragma unroll
    for (int j = 0; j < 4; ++j) {
      bitsS[j * 16 + wave * 2 + 0][64 + lane] = alo[j];
      bitsS[j * 16 + wave * 2 + 1][64 + lane] = ahi[j];
    }
  }
  __syncthreads();
  f32x4 acc = {0.f, 0.f, 0.f, 0.f};
  const int trow = wave * 16 + (lane & 15);
  const int shift = (lane >> 4) * 8;
  for (int c = 0; c < 8; ++c) {
    PhiS[wave][lane] = *(const uint4*)(Phi + (size_t)((c * 8 + wave) * 64 + lane) * 4);
    PloS[wave][lane] = *(const uint4*)(Plo + (size_t)((c * 8 + wave) * 64 + lane) * 4);
    __syncthreads();
    if (wave < 7) {
#pragma unroll
      for (int kk = 0; kk < 8; ++kk) {
        u32 w8 = (bitsS[c * 8 + kk][trow] >> shift) & 0xFFu;
        u32 u = w8 | (w8 << 15);
        uint4 a0u;
        ((u32*)&a0u)[0] = ( u        & 0x00010001u) * 0x3F80u;
        ((u32*)&a0u)[1] = ((u >> 2)  & 0x00010001u) * 0x3F80u;
        ((u32*)&a0u)[2] = ((u >> 4)  & 0x00010001u) * 0x3F80u;
        ((u32*)&a0u)[3] = ((u >> 6)  & 0x00010001u) * 0x3F80u;
        s16x8 a   = __builtin_bit_cast(s16x8, a0u);
        s16x8 bhi = __builtin_bit_cast(s16x8, PhiS[kk][lane]);
        s16x8 blo = __builtin_bit_cast(s16x8, PloS[kk][lane]);
        acc = __builtin_amdgcn_mfma_f32_16x16x32_bf16(a, bhi, acc, 0, 0, 0);
        acc = __builtin_amdgcn_mfma_f32_16x16x32_bf16(a, blo, acc, 0, 0, 0);
      }
    }
    __syncthreads();
  }
  if (wave < 7) {
    const int colw = lane & 15, rbase = (lane >> 4) * 4;
#pragma unroll
    for (int r = 0; r < 4; ++r) c2[wave * 16 + rbase + r][colw] = acc[r];
  }
  __syncthreads();
  if (tid < 16) {
    const int o = tid;
    const bool valid = (o < D_O);
    const float bb = valid ? b2[o] : 0.0f;
    float m2 = 0.0f; bool s2 = false; int cnt = 0;
    for (int t0 = 0; t0 < T_STEPS; t0 += 10) {
      float cc[10];
#pragma unroll
      for (int i = 0; i < 10; ++i) cc[i] = c2[t0 + i][o];
#pragma unroll
      for (int i = 0; i < 10; ++i) {
        float cI = __fadd_rn(cc[i], bb);
        float m = __fadd_rn(__fmul_rn(b2c, m2), cI);
        if (s2) m = __fsub_rn(m, 1.0f);
        s2 = (m > 1.0f);
        m2 = m;
        cnt += s2 ? 1 : 0;
      }
    }
    float mean = valid ? ((float)cnt / 100.0f) : -1e30f;
    float mx = mean;
#pragma unroll
    for (int i = 8; i >= 1; i >>= 1) mx = fmaxf(mx, __shfl_xor(mx, i, 16));
    float e = valid ? expf(mean - mx) : 0.0f;
    float s = e;
#pragma unroll
    for (int i = 8; i >= 1; i >>= 1) s = __fadd_rn(s, __shfl_xor(s, i, 16));
    if (valid) out[(size_t)b * D_O + o] = e / s;
  }
}

// ---------------------------------------------------------------------------
extern "C" void kernel_launch(void* const* d_in, const int* in_sizes, int n_in,
                              void* d_out, int out_size, void* d_ws, size_t ws_size,
                              hipStream_t stream) {
  const float* x     = (const float*)d_in[0];
  const float* W1    = (const float*)d_in[1];
  const float* b1    = (const float*)d_in[2];
  const float* W2    = (const float*)d_in[3];
  const float* b2    = (const float*)d_in[4];
  const float* beta1 = (const float*)d_in[5];
  const float* beta2 = (const float*)d_in[6];
  float* out = (float*)d_out;

  char* ws = (char*)d_ws;
  // base layout: [0,4M) cur1 | [4M,+64K) Phi | [+64K,+64K) Plo |
  //              [4,325,376..) Xs | [6,782,976..16,613,376) Ws
  // overlays: bits over Xs/Ws (dead after k_gemm1): [4,325,376..19,005,440)
  //           c2g over cur1 (dead after k2a):       [0 .. 3,670,016)
  float* cur1 = (float*)ws;
  u32*   Phi  = (u32*)(ws + 4194304);
  u32*   Plo  = (u32*)(ws + 4259840);
  uint4* Xs   = (uint4*)(ws + 4325376);
  uint4* Ws_  = (uint4*)(ws + 6782976);
  u32*   bits = (u32*)(ws + 4325376);
  float* c2g  = (float*)ws;
  const bool big = (ws_size >= 19005440u);

  hipLaunchKernelGGL(k_prep_w2, dim3(16), dim3(256), 0, stream, W2, Phi, Plo);
  hipLaunchKernelGGL(k_split, dim3(1000), dim3(256), 0, stream, x, W1, Xs, Ws_);
  hipLaunchKernelGGL(k_gemm1, dim3(32, 8), dim3(512), 0, stream, Xs, Ws_, b1, cur1);
  if (big) {
    hipLaunchKernelGGL(k2a, dim3(2048), dim3(256), 0, stream, cur1, beta1, bits);
    hipLaunchKernelGGL(k2b, dim3(512), dim3(512), 0, stream, bits, Phi, Plo, c2g);
    hipLaunchKernelGGL(k2c, dim3(64), dim3(128), 0, stream, c2g, b2, beta2, out);
  } else {
    hipLaunchKernelGGL(k_snn2, dim3(512), dim3(512), 0, stream,
                       cur1, Phi, Plo, b2, beta1, beta2, out);
  }
}

// Round 9
// 73.985 us; speedup vs baseline: 1.4058x; 1.4058x over previous
//
#include <hip/hip_runtime.h>
#include <cstdint>

typedef unsigned int u32;
typedef unsigned short u16;
typedef unsigned long long u64;
typedef __attribute__((ext_vector_type(4))) float f32x4;
typedef __attribute__((ext_vector_type(8))) short s16x8;

#define D_IN   784
#define D_H    2048
#define D_O    10
#define T_STEPS 100

static __device__ __forceinline__ u16 f2bf_rn(float f) {
  u32 u = __float_as_uint(f);
  u32 r = u + 0x7FFFu + ((u >> 16) & 1u);
  return (u16)(r >> 16);
}
static __device__ __forceinline__ float bf2f(u16 h) {
  return __uint_as_float(((u32)h) << 16);
}

// Truncation-based triple-split of an f32 pair into three packed bf16-pair
// words. r = f - trunc16(f) is exact; dropped residual <= 2^-24 * |f|.
static __device__ __forceinline__ void packpair(float f0, float f1,
                                                u32& o0, u32& o1, u32& o2) {
  u32 u0 = __float_as_uint(f0), u1 = __float_as_uint(f1);
  o0 = (u0 >> 16) | (u1 & 0xFFFF0000u);
  float r0 = __fsub_rn(f0, __uint_as_float(u0 & 0xFFFF0000u));
  float r1 = __fsub_rn(f1, __uint_as_float(u1 & 0xFFFF0000u));
  u32 v0 = __float_as_uint(r0), v1 = __float_as_uint(r1);
  o1 = (v0 >> 16) | (v1 & 0xFFFF0000u);
  float s0 = __fsub_rn(r0, __uint_as_float(v0 & 0xFFFF0000u));
  float s1 = __fsub_rn(r1, __uint_as_float(v1 & 0xFFFF0000u));
  o2 = (__float_as_uint(s0) >> 16) | (__float_as_uint(s1) & 0xFFFF0000u);
}

// ---------------------------------------------------------------------------
// K0: W2 (f32) -> bf16 hi/lo MFMA B-fragments (round-1/3 verbatim, verified).
// ---------------------------------------------------------------------------
__global__ __launch_bounds__(256) void k_prep_w2(const float* __restrict__ W2,
                                                 u32* __restrict__ Phi,
                                                 u32* __restrict__ Plo) {
  int t = blockIdx.x * 256 + threadIdx.x;
  if (t >= 64 * 64) return;
  int kb = t >> 6, l = t & 63;
  int o = l & 15;
  int kbase = kb * 32 + ((l >> 4) << 3);
  u32 hw[4], lw[4];
#pragma unroll
  for (int p = 0; p < 4; ++p) {
    u32 hp = 0, lp = 0;
#pragma unroll
    for (int q = 0; q < 2; ++q) {
      float f = (o < D_O) ? W2[o * D_H + kbase + 2 * p + q] : 0.0f;
      u16 h = f2bf_rn(f);
      float rr = __fsub_rn(f, bf2f(h));
      u16 lo = f2bf_rn(rr);
      hp |= ((u32)h) << (16 * q);
      lp |= ((u32)lo) << (16 * q);
    }
    hw[p] = hp; lw[p] = lp;
  }
  int base = (kb * 64 + l) * 4;
#pragma unroll
  for (int p = 0; p < 4; ++p) { Phi[base + p] = hw[p]; Plo[base + p] = lw[p]; }
}

// ---------------------------------------------------------------------------
// K1: FUSED split+GEMM. cur1 = x @ W1^T + b1 via bf16-triple MFMA.
// 64x64 tiles, 256 blocks (1/CU), 512 thr (8 waves = 4 wm x 2 wn).
// XCD-swizzle: xcd = id&7 owns nb in [4*xcd, 4*xcd+4) -> W1 slice (0.8MB)
// + x (1.6MB) fit the 4MiB XCD-L2. Threads 0..255 stage the A(x) tile,
// 256..511 the B(W1) tile; f32 -> triple-bf16 conversion in-register;
// fragments staged in LDS; next-kb global loads prefetched under MFMA.
// ---------------------------------------------------------------------------
__global__ __launch_bounds__(512) void k_fgemm(const float* __restrict__ x,
                                               const float* __restrict__ W1,
                                               const float* __restrict__ b1,
                                               float* __restrict__ cur1) {
  __shared__ uint4 As[3][4][64];   // 12 KB
  __shared__ uint4 Bs[3][4][64];   // 12 KB
  const int tid = threadIdx.x, wave = tid >> 6, lane = tid & 63;
  const int id = blockIdx.x;
  const int sub = id >> 3;                  // 0..31
  const int mb = sub >> 2;                  // 0..7   (batch-row tile)
  const int nb = (id & 7) * 4 + (sub & 3);  // 0..31  (hidden-col tile)
  const int wm = wave >> 1, wn = wave & 1;
  const int st = tid & 255;
  const int srow = st >> 2, skq = st & 3;
  const int sfrag = srow >> 4;
  const int slane = skq * 16 + (srow & 15);
  const bool isA = (tid < 256);
  const float* srcrow = isA ? (x  + (size_t)(mb * 64 + srow) * D_IN)
                            : (W1 + (size_t)(nb * 64 + srow) * D_IN);
  f32x4 acc0 = {0.f, 0.f, 0.f, 0.f}, acc1 = {0.f, 0.f, 0.f, 0.f};
  float e[8];
  {
    const int kg = skq * 8;                 // < 784 always
    float4 v0 = *(const float4*)(srcrow + kg);
    float4 v1 = *(const float4*)(srcrow + kg + 4);
    e[0] = v0.x; e[1] = v0.y; e[2] = v0.z; e[3] = v0.w;
    e[4] = v1.x; e[5] = v1.y; e[6] = v1.z; e[7] = v1.w;
  }
  for (int kb = 0; kb < 25; ++kb) {
    u32 w0[4], w1[4], w2[4];
#pragma unroll
    for (int p = 0; p < 4; ++p) packpair(e[2 * p], e[2 * p + 1], w0[p], w1[p], w2[p]);
    __syncthreads();   // previous iteration's readers are done
    if (isA) {
      As[0][sfrag][slane] = make_uint4(w0[0], w0[1], w0[2], w0[3]);
      As[1][sfrag][slane] = make_uint4(w1[0], w1[1], w1[2], w1[3]);
      As[2][sfrag][slane] = make_uint4(w2[0], w2[1], w2[2], w2[3]);
    } else {
      Bs[0][sfrag][slane] = make_uint4(w0[0], w0[1], w0[2], w0[3]);
      Bs[1][sfrag][slane] = make_uint4(w1[0], w1[1], w1[2], w1[3]);
      Bs[2][sfrag][slane] = make_uint4(w2[0], w2[1], w2[2], w2[3]);
    }
    __syncthreads();
    if (kb < 24) {     // prefetch next k-chunk under the MFMAs
      const int kg = (kb + 1) * 32 + skq * 8;
      if (kg < D_IN) {
        float4 v0 = *(const float4*)(srcrow + kg);
        float4 v1 = *(const float4*)(srcrow + kg + 4);
        e[0] = v0.x; e[1] = v0.y; e[2] = v0.z; e[3] = v0.w;
        e[4] = v1.x; e[5] = v1.y; e[6] = v1.z; e[7] = v1.w;
      } else {
#pragma unroll
        for (int q = 0; q < 8; ++q) e[q] = 0.0f;
      }
    }
    s16x8 A0 = __builtin_bit_cast(s16x8, As[0][wm][lane]);
    s16x8 A1 = __builtin_bit_cast(s16x8, As[1][wm][lane]);
    s16x8 A2 = __builtin_bit_cast(s16x8, As[2][wm][lane]);
    {
      s16x8 B0 = __builtin_bit_cast(s16x8, Bs[0][wn * 2][lane]);
      s16x8 B1 = __builtin_bit_cast(s16x8, Bs[1][wn * 2][lane]);
      s16x8 B2 = __builtin_bit_cast(s16x8, Bs[2][wn * 2][lane]);
      acc0 = __builtin_amdgcn_mfma_f32_16x16x32_bf16(A0, B0, acc0, 0, 0, 0);
      acc0 = __builtin_amdgcn_mfma_f32_16x16x32_bf16(A0, B1, acc0, 0, 0, 0);
      acc0 = __builtin_amdgcn_mfma_f32_16x16x32_bf16(A1, B0, acc0, 0, 0, 0);
      acc0 = __builtin_amdgcn_mfma_f32_16x16x32_bf16(A1, B1, acc0, 0, 0, 0);
      acc0 = __builtin_amdgcn_mfma_f32_16x16x32_bf16(A0, B2, acc0, 0, 0, 0);
      acc0 = __builtin_amdgcn_mfma_f32_16x16x32_bf16(A2, B0, acc0, 0, 0, 0);
    }
    {
      s16x8 B0 = __builtin_bit_cast(s16x8, Bs[0][wn * 2 + 1][lane]);
      s16x8 B1 = __builtin_bit_cast(s16x8, Bs[1][wn * 2 + 1][lane]);
      s16x8 B2 = __builtin_bit_cast(s16x8, Bs[2][wn * 2 + 1][lane]);
      acc1 = __builtin_amdgcn_mfma_f32_16x16x32_bf16(A0, B0, acc1, 0, 0, 0);
      acc1 = __builtin_amdgcn_mfma_f32_16x16x32_bf16(A0, B1, acc1, 0, 0, 0);
      acc1 = __builtin_amdgcn_mfma_f32_16x16x32_bf16(A1, B0, acc1, 0, 0, 0);
      acc1 = __builtin_amdgcn_mfma_f32_16x16x32_bf16(A1, B1, acc1, 0, 0, 0);
      acc1 = __builtin_amdgcn_mfma_f32_16x16x32_bf16(A0, B2, acc1, 0, 0, 0);
      acc1 = __builtin_amdgcn_mfma_f32_16x16x32_bf16(A2, B0, acc1, 0, 0, 0);
    }
  }
  const int col = lane & 15, rb = (lane >> 4) * 4;
  {
    const int gcol = nb * 64 + (wn * 2) * 16 + col;
    const float bv = b1[gcol];
#pragma unroll
    for (int r = 0; r < 4; ++r)
      cur1[(size_t)(mb * 64 + wm * 16 + rb + r) * D_H + gcol] = acc0[r] + bv;
  }
  {
    const int gcol = nb * 64 + (wn * 2 + 1) * 16 + col;
    const float bv = b1[gcol];
#pragma unroll
    for (int r = 0; r < 4; ++r)
      cur1[(size_t)(mb * 64 + wm * 16 + rb + r) * D_H + gcol] = acc1[r] + bv;
  }
}

// ---------------------------------------------------------------------------
// K2: fused temporal kernel (round-7 verbatim, measured 44.4us).
// ---------------------------------------------------------------------------
__global__ __launch_bounds__(512) void k_snn2(const float* __restrict__ cur1,
                                              const u32* __restrict__ Phi,
                                              const u32* __restrict__ Plo,
                                              const float* __restrict__ b2,
                                              const float* __restrict__ beta1p,
                                              const float* __restrict__ beta2p,
                                              float* __restrict__ out) {
  __shared__ u32  bitsS[64][112];   // [h32][t], 28 KB
  __shared__ uint4 PhiS[8][64];     // 8 KB
  __shared__ uint4 PloS[8][64];     // 8 KB
  __shared__ float c2[112][18];     // 8 KB
  const int b = blockIdx.x, tid = threadIdx.x;
  const int wave = tid >> 6, lane = tid & 63;
  const float b1c = fminf(fmaxf(beta1p[0], 0.0f), 1.0f);
  const float b2c = fminf(fmaxf(beta2p[0], 0.0f), 1.0f);

  float cv[4], memv[4]; bool sp[4];
  u32 alo[4], ahi[4];
#pragma unroll
  for (int j = 0; j < 4; ++j) {
    cv[j] = cur1[(size_t)b * D_H + j * 512 + tid];
    memv[j] = 0.0f; sp[j] = false; alo[j] = 0u; ahi[j] = 0u;
  }
  for (int t = 0; t < 64; ++t) {
    const bool mine = (lane == t);
#pragma unroll
    for (int j = 0; j < 4; ++j) {
      float m = __fmul_rn(b1c, memv[j]);
      m = __fadd_rn(m, cv[j]);
      if (sp[j]) m = __fsub_rn(m, 1.0f);
      sp[j] = (m > 1.0f);
      memv[j] = m;
      u64 msk = __ballot(sp[j]);
      alo[j] = mine ? (u32)msk : alo[j];
      ahi[j] = mine ? (u32)(msk >> 32) : ahi[j];
    }
  }
#pragma unroll
  for (int j = 0; j < 4; ++j) {
    bitsS[j * 16 + wave * 2 + 0][lane] = alo[j];
    bitsS[j * 16 + wave * 2 + 1][lane] = ahi[j];
    alo[j] = 0u; ahi[j] = 0u;
  }
  for (int t = 64; t < T_STEPS; ++t) {
    const bool mine = (lane == t - 64);
#pragma unroll
    for (int j = 0; j < 4; ++j) {
      float m = __fmul_rn(b1c, memv[j]);
      m = __fadd_rn(m, cv[j]);
      if (sp[j]) m = __fsub_rn(m, 1.0f);
      sp[j] = (m > 1.0f);
      memv[j] = m;
      u64 msk = __ballot(sp[j]);
      alo[j] = mine ? (u32)msk : alo[j];
      ahi[j] = mine ? (u32)(msk >> 32) : ahi[j];
    }
  }
  if (lane < 48) {
#pragma unroll
    for (int j = 0; j < 4; ++j) {
      bitsS[j * 16 + wave * 2 + 0][64 + lane] = alo[j];
      bitsS[j * 16 + wave * 2 + 1][64 + lane] = ahi[j];
    }
  }
  __syncthreads();

  f32x4 acc = {0.f, 0.f, 0.f, 0.f};
  const int trow = wave * 16 + (lane & 15);
  const int shift = (lane >> 4) * 8;
  for (int c = 0; c < 8; ++c) {
    PhiS[wave][lane] = *(const uint4*)(Phi + (size_t)((c * 8 + wave) * 64 + lane) * 4);
    PloS[wave][lane] = *(const uint4*)(Plo + (size_t)((c * 8 + wave) * 64 + lane) * 4);
    __syncthreads();
    if (wave < 7) {
#pragma unroll
      for (int kk = 0; kk < 8; ++kk) {
        u32 w8 = (bitsS[c * 8 + kk][trow] >> shift) & 0xFFu;
        u32 u = w8 | (w8 << 15);
        uint4 a0u;
        ((u32*)&a0u)[0] = ( u        & 0x00010001u) * 0x3F80u;
        ((u32*)&a0u)[1] = ((u >> 2)  & 0x00010001u) * 0x3F80u;
        ((u32*)&a0u)[2] = ((u >> 4)  & 0x00010001u) * 0x3F80u;
        ((u32*)&a0u)[3] = ((u >> 6)  & 0x00010001u) * 0x3F80u;
        s16x8 a   = __builtin_bit_cast(s16x8, a0u);
        s16x8 bhi = __builtin_bit_cast(s16x8, PhiS[kk][lane]);
        s16x8 blo = __builtin_bit_cast(s16x8, PloS[kk][lane]);
        acc = __builtin_amdgcn_mfma_f32_16x16x32_bf16(a, bhi, acc, 0, 0, 0);
        acc = __builtin_amdgcn_mfma_f32_16x16x32_bf16(a, blo, acc, 0, 0, 0);
      }
    }
    __syncthreads();
  }
  if (wave < 7) {
    const int colw = lane & 15, rbase = (lane >> 4) * 4;
#pragma unroll
    for (int r = 0; r < 4; ++r) c2[wave * 16 + rbase + r][colw] = acc[r];
  }
  __syncthreads();

  if (tid < 16) {
    const int o = tid;
    const bool valid = (o < D_O);
    const float bb = valid ? b2[o] : 0.0f;
    float m2 = 0.0f; bool s2 = false; int cnt = 0;
    for (int t0 = 0; t0 < T_STEPS; t0 += 10) {
      float cc[10];
#pragma unroll
      for (int i = 0; i < 10; ++i) cc[i] = c2[t0 + i][o];
#pragma unroll
      for (int i = 0; i < 10; ++i) {
        float cI = __fadd_rn(cc[i], bb);
        float m = __fadd_rn(__fmul_rn(b2c, m2), cI);
        if (s2) m = __fsub_rn(m, 1.0f);
        s2 = (m > 1.0f);
        m2 = m;
        cnt += s2 ? 1 : 0;
      }
    }
    float mean = valid ? ((float)cnt / 100.0f) : -1e30f;
    float mx = mean;
#pragma unroll
    for (int i = 8; i >= 1; i >>= 1) mx = fmaxf(mx, __shfl_xor(mx, i, 16));
    float e = valid ? expf(mean - mx) : 0.0f;
    float s = e;
#pragma unroll
    for (int i = 8; i >= 1; i >>= 1) s = __fadd_rn(s, __shfl_xor(s, i, 16));
    if (valid) out[(size_t)b * D_O + o] = e / s;
  }
}

// ---------------------------------------------------------------------------
extern "C" void kernel_launch(void* const* d_in, const int* in_sizes, int n_in,
                              void* d_out, int out_size, void* d_ws, size_t ws_size,
                              hipStream_t stream) {
  const float* x     = (const float*)d_in[0];
  const float* W1    = (const float*)d_in[1];
  const float* b1    = (const float*)d_in[2];
  const float* W2    = (const float*)d_in[3];
  const float* b2    = (const float*)d_in[4];
  const float* beta1 = (const float*)d_in[5];
  const float* beta2 = (const float*)d_in[6];
  float* out = (float*)d_out;

  char* ws = (char*)d_ws;
  // layout: [0, 4M) cur1 | [4M, 4M+64K) Phi | [4M+64K, 4M+128K) Plo
  float* cur1 = (float*)ws;
  u32*   Phi  = (u32*)(ws + 4194304);
  u32*   Plo  = (u32*)(ws + 4259840);

  hipLaunchKernelGGL(k_prep_w2, dim3(16), dim3(256), 0, stream, W2, Phi, Plo);
  hipLaunchKernelGGL(k_fgemm, dim3(256), dim3(512), 0, stream, x, W1, b1, cur1);
  hipLaunchKernelGGL(k_snn2, dim3(512), dim3(512), 0, stream,
                     cur1, Phi, Plo, b2, beta1, beta2, out);
}

// Round 11
// 69.870 us; speedup vs baseline: 1.4886x; 1.0589x over previous
//
#include <hip/hip_runtime.h>
#include <cstdint>

typedef unsigned int u32;
typedef unsigned short u16;
typedef unsigned long long u64;
typedef __attribute__((ext_vector_type(4))) float f32x4;
typedef __attribute__((ext_vector_type(8))) short s16x8;

#define D_IN   784
#define D_H    2048
#define D_O    10
#define T_STEPS 100

static __device__ __forceinline__ u16 f2bf_rn(float f) {
  u32 u = __float_as_uint(f);
  u32 r = u + 0x7FFFu + ((u >> 16) & 1u);
  return (u16)(r >> 16);
}
static __device__ __forceinline__ float bf2f(u16 h) {
  return __uint_as_float(((u32)h) << 16);
}

// Truncation-based triple-split of an f32 pair into three packed bf16-pair
// words. r = f - trunc16(f) is exact; dropped residual <= 2^-24 * |f|.
static __device__ __forceinline__ void packpair(float f0, float f1,
                                                u32& o0, u32& o1, u32& o2) {
  u32 u0 = __float_as_uint(f0), u1 = __float_as_uint(f1);
  o0 = (u0 >> 16) | (u1 & 0xFFFF0000u);
  float r0 = __fsub_rn(f0, __uint_as_float(u0 & 0xFFFF0000u));
  float r1 = __fsub_rn(f1, __uint_as_float(u1 & 0xFFFF0000u));
  u32 v0 = __float_as_uint(r0), v1 = __float_as_uint(r1);
  o1 = (v0 >> 16) | (v1 & 0xFFFF0000u);
  float s0 = __fsub_rn(r0, __uint_as_float(v0 & 0xFFFF0000u));
  float s1 = __fsub_rn(r1, __uint_as_float(v1 & 0xFFFF0000u));
  o2 = (__float_as_uint(s0) >> 16) | (__float_as_uint(s1) & 0xFFFF0000u);
}

// ---------------------------------------------------------------------------
// K0: W2 (f32) -> bf16 hi/lo MFMA B-fragments (round-1/3 verbatim, verified).
// ---------------------------------------------------------------------------
__global__ __launch_bounds__(256) void k_prep_w2(const float* __restrict__ W2,
                                                 u32* __restrict__ Phi,
                                                 u32* __restrict__ Plo) {
  int t = blockIdx.x * 256 + threadIdx.x;
  if (t >= 64 * 64) return;
  int kb = t >> 6, l = t & 63;
  int o = l & 15;
  int kbase = kb * 32 + ((l >> 4) << 3);
  u32 hw[4], lw[4];
#pragma unroll
  for (int p = 0; p < 4; ++p) {
    u32 hp = 0, lp = 0;
#pragma unroll
    for (int q = 0; q < 2; ++q) {
      float f = (o < D_O) ? W2[o * D_H + kbase + 2 * p + q] : 0.0f;
      u16 h = f2bf_rn(f);
      float rr = __fsub_rn(f, bf2f(h));
      u16 lo = f2bf_rn(rr);
      hp |= ((u32)h) << (16 * q);
      lp |= ((u32)lo) << (16 * q);
    }
    hw[p] = hp; lw[p] = lp;
  }
  int base = (kb * 64 + l) * 4;
#pragma unroll
  for (int p = 0; p < 4; ++p) { Phi[base + p] = hw[p]; Plo[base + p] = lw[p]; }
}

// ---------------------------------------------------------------------------
// K1: FUSED split+GEMM (round-9 verbatim). cur1 = x @ W1^T + b1.
// ---------------------------------------------------------------------------
__global__ __launch_bounds__(512) void k_fgemm(const float* __restrict__ x,
                                               const float* __restrict__ W1,
                                               const float* __restrict__ b1,
                                               float* __restrict__ cur1) {
  __shared__ uint4 As[3][4][64];   // 12 KB
  __shared__ uint4 Bs[3][4][64];   // 12 KB
  const int tid = threadIdx.x, wave = tid >> 6, lane = tid & 63;
  const int id = blockIdx.x;
  const int sub = id >> 3;                  // 0..31
  const int mb = sub >> 2;                  // 0..7   (batch-row tile)
  const int nb = (id & 7) * 4 + (sub & 3);  // 0..31  (hidden-col tile)
  const int wm = wave >> 1, wn = wave & 1;
  const int st = tid & 255;
  const int srow = st >> 2, skq = st & 3;
  const int sfrag = srow >> 4;
  const int slane = skq * 16 + (srow & 15);
  const bool isA = (tid < 256);
  const float* srcrow = isA ? (x  + (size_t)(mb * 64 + srow) * D_IN)
                            : (W1 + (size_t)(nb * 64 + srow) * D_IN);
  f32x4 acc0 = {0.f, 0.f, 0.f, 0.f}, acc1 = {0.f, 0.f, 0.f, 0.f};
  float e[8];
  {
    const int kg = skq * 8;                 // < 784 always
    float4 v0 = *(const float4*)(srcrow + kg);
    float4 v1 = *(const float4*)(srcrow + kg + 4);
    e[0] = v0.x; e[1] = v0.y; e[2] = v0.z; e[3] = v0.w;
    e[4] = v1.x; e[5] = v1.y; e[6] = v1.z; e[7] = v1.w;
  }
  for (int kb = 0; kb < 25; ++kb) {
    u32 w0[4], w1[4], w2[4];
#pragma unroll
    for (int p = 0; p < 4; ++p) packpair(e[2 * p], e[2 * p + 1], w0[p], w1[p], w2[p]);
    __syncthreads();   // previous iteration's readers are done
    if (isA) {
      As[0][sfrag][slane] = make_uint4(w0[0], w0[1], w0[2], w0[3]);
      As[1][sfrag][slane] = make_uint4(w1[0], w1[1], w1[2], w1[3]);
      As[2][sfrag][slane] = make_uint4(w2[0], w2[1], w2[2], w2[3]);
    } else {
      Bs[0][sfrag][slane] = make_uint4(w0[0], w0[1], w0[2], w0[3]);
      Bs[1][sfrag][slane] = make_uint4(w1[0], w1[1], w1[2], w1[3]);
      Bs[2][sfrag][slane] = make_uint4(w2[0], w2[1], w2[2], w2[3]);
    }
    __syncthreads();
    if (kb < 24) {     // prefetch next k-chunk under the MFMAs
      const int kg = (kb + 1) * 32 + skq * 8;
      if (kg < D_IN) {
        float4 v0 = *(const float4*)(srcrow + kg);
        float4 v1 = *(const float4*)(srcrow + kg + 4);
        e[0] = v0.x; e[1] = v0.y; e[2] = v0.z; e[3] = v0.w;
        e[4] = v1.x; e[5] = v1.y; e[6] = v1.z; e[7] = v1.w;
      } else {
#pragma unroll
        for (int q = 0; q < 8; ++q) e[q] = 0.0f;
      }
    }
    s16x8 A0 = __builtin_bit_cast(s16x8, As[0][wm][lane]);
    s16x8 A1 = __builtin_bit_cast(s16x8, As[1][wm][lane]);
    s16x8 A2 = __builtin_bit_cast(s16x8, As[2][wm][lane]);
    {
      s16x8 B0 = __builtin_bit_cast(s16x8, Bs[0][wn * 2][lane]);
      s16x8 B1 = __builtin_bit_cast(s16x8, Bs[1][wn * 2][lane]);
      s16x8 B2 = __builtin_bit_cast(s16x8, Bs[2][wn * 2][lane]);
      acc0 = __builtin_amdgcn_mfma_f32_16x16x32_bf16(A0, B0, acc0, 0, 0, 0);
      acc0 = __builtin_amdgcn_mfma_f32_16x16x32_bf16(A0, B1, acc0, 0, 0, 0);
      acc0 = __builtin_amdgcn_mfma_f32_16x16x32_bf16(A1, B0, acc0, 0, 0, 0);
      acc0 = __builtin_amdgcn_mfma_f32_16x16x32_bf16(A1, B1, acc0, 0, 0, 0);
      acc0 = __builtin_amdgcn_mfma_f32_16x16x32_bf16(A0, B2, acc0, 0, 0, 0);
      acc0 = __builtin_amdgcn_mfma_f32_16x16x32_bf16(A2, B0, acc0, 0, 0, 0);
    }
    {
      s16x8 B0 = __builtin_bit_cast(s16x8, Bs[0][wn * 2 + 1][lane]);
      s16x8 B1 = __builtin_bit_cast(s16x8, Bs[1][wn * 2 + 1][lane]);
      s16x8 B2 = __builtin_bit_cast(s16x8, Bs[2][wn * 2 + 1][lane]);
      acc1 = __builtin_amdgcn_mfma_f32_16x16x32_bf16(A0, B0, acc1, 0, 0, 0);
      acc1 = __builtin_amdgcn_mfma_f32_16x16x32_bf16(A0, B1, acc1, 0, 0, 0);
      acc1 = __builtin_amdgcn_mfma_f32_16x16x32_bf16(A1, B0, acc1, 0, 0, 0);
      acc1 = __builtin_amdgcn_mfma_f32_16x16x32_bf16(A1, B1, acc1, 0, 0, 0);
      acc1 = __builtin_amdgcn_mfma_f32_16x16x32_bf16(A0, B2, acc1, 0, 0, 0);
      acc1 = __builtin_amdgcn_mfma_f32_16x16x32_bf16(A2, B0, acc1, 0, 0, 0);
    }
  }
  const int col = lane & 15, rb = (lane >> 4) * 4;
  {
    const int gcol = nb * 64 + (wn * 2) * 16 + col;
    const float bv = b1[gcol];
#pragma unroll
    for (int r = 0; r < 4; ++r)
      cur1[(size_t)(mb * 64 + wm * 16 + rb + r) * D_H + gcol] = acc0[r] + bv;
  }
  {
    const int gcol = nb * 64 + (wn * 2 + 1) * 16 + col;
    const float bv = b1[gcol];
#pragma unroll
    for (int r = 0; r < 4; ++r)
      cur1[(size_t)(mb * 64 + wm * 16 + rb + r) * D_H + gcol] = acc1[r] + bv;
  }
}

// ---------------------------------------------------------------------------
// K2: fused temporal kernel, BRANCHLESS phase B.
//  Reference computes mem = b*mem + cur - reset*THR: reset*THR is ALWAYS
//  subtracted (0.0 when no spike; m - 0.0 == m exactly). So: one cndmask
//  (spf = sp ? 1.0 : 0.0) + unconditional fsub -- no exec-mask regions,
//  bit-identical op order. Capture: lane0 ds_write_b64 (off the VALU pipe).
//  Phase C: direct-global Phi/Plo (R3-measured-equal to staging, no barriers).
// ---------------------------------------------------------------------------
__global__ __launch_bounds__(512) void k_snn3(const float* __restrict__ cur1,
                                              const u32* __restrict__ Phi,
                                              const u32* __restrict__ Plo,
                                              const float* __restrict__ b2,
                                              const float* __restrict__ beta1p,
                                              const float* __restrict__ beta2p,
                                              float* __restrict__ out) {
  __shared__ __align__(16) u32 bits[112][66];   // [t][h32], 29.6 KB
  __shared__ float c2[112][18];                 // 8 KB
  const int b = blockIdx.x;
  const int tid = threadIdx.x;
  const int wave = tid >> 6, lane = tid & 63;
  const float b1c = fminf(fmaxf(beta1p[0], 0.0f), 1.0f);
  const float b2c = fminf(fmaxf(beta2p[0], 0.0f), 1.0f);

  // zero the A-padding rows (t = 100..111)
  for (int idx = tid; idx < 12 * 66; idx += 512) bits[100 + idx / 66][idx % 66] = 0;

  // ---- phase B: branchless layer-1 recurrence ----
  float cv[4], memv[4], spf[4];
#pragma unroll
  for (int j = 0; j < 4; ++j) {
    cv[j] = cur1[(size_t)b * D_H + j * 512 + tid];
    memv[j] = 0.0f; spf[j] = 0.0f;
  }
  for (int t = 0; t < T_STEPS; ++t) {
    u64 msk[4];
#pragma unroll
    for (int j = 0; j < 4; ++j) {
      float m = __fmul_rn(b1c, memv[j]);     // b*mem
      m = __fadd_rn(m, cv[j]);               // + cur
      m = __fsub_rn(m, spf[j]);              // - reset*THR (always; 0.0 ok)
      bool sp = (m > 1.0f);
      msk[j] = __ballot(sp);
      spf[j] = sp ? 1.0f : 0.0f;
      memv[j] = m;
    }
    if (lane == 0) {
      u64* rowp = (u64*)&bits[t][0];
      rowp[0 * 8 + wave] = msk[0];
      rowp[1 * 8 + wave] = msk[1];
      rowp[2 * 8 + wave] = msk[2];
      rowp[3 * 8 + wave] = msk[3];
    }
  }
  __syncthreads();

  // ---- phase C: cur2 via MFMA (waves 0..6), direct-global Phi/Plo ----
  if (wave < 7) {
    f32x4 acc = {0.f, 0.f, 0.f, 0.f};
    const int row0 = wave * 16 + (lane & 15);
    const int shift = (lane >> 4) * 8;
    for (int kb = 0; kb < 64; ++kb) {
      const uint4 bh = *(const uint4*)(Phi + (size_t)(kb * 64 + lane) * 4);
      const uint4 bl = *(const uint4*)(Plo + (size_t)(kb * 64 + lane) * 4);
      u32 w8 = (bits[row0][kb] >> shift) & 0xFFu;
      u32 u = w8 | (w8 << 15);
      uint4 a0u;
      ((u32*)&a0u)[0] = ( u        & 0x00010001u) * 0x3F80u;
      ((u32*)&a0u)[1] = ((u >> 2)  & 0x00010001u) * 0x3F80u;
      ((u32*)&a0u)[2] = ((u >> 4)  & 0x00010001u) * 0x3F80u;
      ((u32*)&a0u)[3] = ((u >> 6)  & 0x00010001u) * 0x3F80u;
      s16x8 a   = __builtin_bit_cast(s16x8, a0u);
      s16x8 bhi = __builtin_bit_cast(s16x8, bh);
      s16x8 blo = __builtin_bit_cast(s16x8, bl);
      acc = __builtin_amdgcn_mfma_f32_16x16x32_bf16(a, bhi, acc, 0, 0, 0);
      acc = __builtin_amdgcn_mfma_f32_16x16x32_bf16(a, blo, acc, 0, 0, 0);
    }
    const int colw = lane & 15, rbase = (lane >> 4) * 4;
#pragma unroll
    for (int r = 0; r < 4; ++r) c2[wave * 16 + rbase + r][colw] = acc[r];
  }
  __syncthreads();

  // ---- phase D: layer-2 recurrence + mean + softmax (batched c2 reads) ----
  if (tid < 16) {
    const int o = tid;
    const bool valid = (o < D_O);
    const float bb = valid ? b2[o] : 0.0f;
    float m2 = 0.0f; bool s2 = false; int cnt = 0;
    for (int t0 = 0; t0 < T_STEPS; t0 += 10) {
      float cc[10];
#pragma unroll
      for (int i = 0; i < 10; ++i) cc[i] = c2[t0 + i][o];
#pragma unroll
      for (int i = 0; i < 10; ++i) {
        float cI = __fadd_rn(cc[i], bb);
        float m = __fadd_rn(__fmul_rn(b2c, m2), cI);
        if (s2) m = __fsub_rn(m, 1.0f);
        s2 = (m > 1.0f);
        m2 = m;
        cnt += s2 ? 1 : 0;
      }
    }
    float mean = valid ? ((float)cnt / 100.0f) : -1e30f;
    float mx = mean;
#pragma unroll
    for (int i = 8; i >= 1; i >>= 1) mx = fmaxf(mx, __shfl_xor(mx, i, 16));
    float e = valid ? expf(mean - mx) : 0.0f;
    float s = e;
#pragma unroll
    for (int i = 8; i >= 1; i >>= 1) s = __fadd_rn(s, __shfl_xor(s, i, 16));
    if (valid) out[(size_t)b * D_O + o] = e / s;
  }
}

// ---------------------------------------------------------------------------
extern "C" void kernel_launch(void* const* d_in, const int* in_sizes, int n_in,
                              void* d_out, int out_size, void* d_ws, size_t ws_size,
                              hipStream_t stream) {
  const float* x     = (const float*)d_in[0];
  const float* W1    = (const float*)d_in[1];
  const float* b1    = (const float*)d_in[2];
  const float* W2    = (const float*)d_in[3];
  const float* b2    = (const float*)d_in[4];
  const float* beta1 = (const float*)d_in[5];
  const float* beta2 = (const float*)d_in[6];
  float* out = (float*)d_out;

  char* ws = (char*)d_ws;
  // layout: [0, 4M) cur1 | [4M, 4M+64K) Phi | [4M+64K, 4M+128K) Plo
  float* cur1 = (float*)ws;
  u32*   Phi  = (u32*)(ws + 4194304);
  u32*   Plo  = (u32*)(ws + 4259840);

  hipLaunchKernelGGL(k_prep_w2, dim3(16), dim3(256), 0, stream, W2, Phi, Plo);
  hipLaunchKernelGGL(k_fgemm, dim3(256), dim3(512), 0, stream, x, W1, b1, cur1);
  hipLaunchKernelGGL(k_snn3, dim3(512), dim3(512), 0, stream,
                     cur1, Phi, Plo, b2, beta1, beta2, out);
}

// Round 12
// 67.255 us; speedup vs baseline: 1.5465x; 1.0389x over previous
//
#include <hip/hip_runtime.h>
#include <cstdint>

typedef unsigned int u32;
typedef unsigned short u16;
typedef unsigned long long u64;
typedef __attribute__((ext_vector_type(4))) float f32x4;
typedef __attribute__((ext_vector_type(8))) short s16x8;

#define D_IN   784
#define D_H    2048
#define D_O    10
#define T_STEPS 100
#define NCOPY  16          // Phi/Plo replication factor (hotspot spread)

static __device__ __forceinline__ u16 f2bf_rn(float f) {
  u32 u = __float_as_uint(f);
  u32 r = u + 0x7FFFu + ((u >> 16) & 1u);
  return (u16)(r >> 16);
}
static __device__ __forceinline__ float bf2f(u16 h) {
  return __uint_as_float(((u32)h) << 16);
}

// Truncation-based triple-split of an f32 pair into three packed bf16-pair
// words. r = f - trunc16(f) is exact; dropped residual <= 2^-24 * |f|.
static __device__ __forceinline__ void packpair(float f0, float f1,
                                                u32& o0, u32& o1, u32& o2) {
  u32 u0 = __float_as_uint(f0), u1 = __float_as_uint(f1);
  o0 = (u0 >> 16) | (u1 & 0xFFFF0000u);
  float r0 = __fsub_rn(f0, __uint_as_float(u0 & 0xFFFF0000u));
  float r1 = __fsub_rn(f1, __uint_as_float(u1 & 0xFFFF0000u));
  u32 v0 = __float_as_uint(r0), v1 = __float_as_uint(r1);
  o1 = (v0 >> 16) | (v1 & 0xFFFF0000u);
  float s0 = __fsub_rn(r0, __uint_as_float(v0 & 0xFFFF0000u));
  float s1 = __fsub_rn(r1, __uint_as_float(v1 & 0xFFFF0000u));
  o2 = (__float_as_uint(s0) >> 16) | (__float_as_uint(s1) & 0xFFFF0000u);
}

// ---------------------------------------------------------------------------
// K0: W2 -> bf16 hi/lo MFMA B-fragments, replicated NCOPY times so k_snn
// blocks spread their reads over 16 distinct copies (L2 slice hotspot fix).
// 256 blocks: copy = blk>>4, sub-block = blk&15. Inner math = R1 verbatim.
// ---------------------------------------------------------------------------
__global__ __launch_bounds__(256) void k_prep_w2(const float* __restrict__ W2,
                                                 u32* __restrict__ Phi,
                                                 u32* __restrict__ Plo) {
  const int blk = blockIdx.x;
  const int copy = blk >> 4;
  int t = (blk & 15) * 256 + threadIdx.x;   // 0..4095
  int kb = t >> 6, l = t & 63;
  int o = l & 15;
  int kbase = kb * 32 + ((l >> 4) << 3);
  u32 hw[4], lw[4];
#pragma unroll
  for (int p = 0; p < 4; ++p) {
    u32 hp = 0, lp = 0;
#pragma unroll
    for (int q = 0; q < 2; ++q) {
      float f = (o < D_O) ? W2[o * D_H + kbase + 2 * p + q] : 0.0f;
      u16 h = f2bf_rn(f);
      float rr = __fsub_rn(f, bf2f(h));
      u16 lo = f2bf_rn(rr);
      hp |= ((u32)h) << (16 * q);
      lp |= ((u32)lo) << (16 * q);
    }
    hw[p] = hp; lw[p] = lp;
  }
  int base = (copy << 15) + (kb * 64 + l) * 4;
#pragma unroll
  for (int p = 0; p < 4; ++p) { Phi[base + p] = hw[p]; Plo[base + p] = lw[p]; }
}

// ---------------------------------------------------------------------------
// K1: FUSED split+GEMM, DOUBLE-BUFFERED LDS (1 barrier/iter; next-kb global
// loads issued at iteration top, packed after the MFMA block so ~12-MFMA +
// 9-ds_read window covers load latency). Arithmetic identical to R9.
// ---------------------------------------------------------------------------
__global__ __launch_bounds__(512) void k_fgemm(const float* __restrict__ x,
                                               const float* __restrict__ W1,
                                               const float* __restrict__ b1,
                                               float* __restrict__ cur1) {
  __shared__ uint4 As[2][3][4][64];   // 24 KB
  __shared__ uint4 Bs[2][3][4][64];   // 24 KB
  const int tid = threadIdx.x, wave = tid >> 6, lane = tid & 63;
  const int id = blockIdx.x;
  const int sub = id >> 3;                  // 0..31
  const int mb = sub >> 2;                  // 0..7   (batch-row tile)
  const int nb = (id & 7) * 4 + (sub & 3);  // 0..31  (hidden-col tile)
  const int wm = wave >> 1, wn = wave & 1;
  const int st = tid & 255;
  const int srow = st >> 2, skq = st & 3;
  const int sfrag = srow >> 4;
  const int slane = skq * 16 + (srow & 15);
  const bool isA = (tid < 256);
  const float* srcrow = isA ? (x  + (size_t)(mb * 64 + srow) * D_IN)
                            : (W1 + (size_t)(nb * 64 + srow) * D_IN);
  f32x4 acc0 = {0.f, 0.f, 0.f, 0.f}, acc1 = {0.f, 0.f, 0.f, 0.f};
  float e[8];
  {
    const int kg = skq * 8;
    float4 v0 = *(const float4*)(srcrow + kg);
    float4 v1 = *(const float4*)(srcrow + kg + 4);
    e[0] = v0.x; e[1] = v0.y; e[2] = v0.z; e[3] = v0.w;
    e[4] = v1.x; e[5] = v1.y; e[6] = v1.z; e[7] = v1.w;
  }
  {  // prologue: pack kb=0 into buffer 0
    u32 w0[4], w1[4], w2[4];
#pragma unroll
    for (int p = 0; p < 4; ++p) packpair(e[2 * p], e[2 * p + 1], w0[p], w1[p], w2[p]);
    if (isA) {
      As[0][0][sfrag][slane] = make_uint4(w0[0], w0[1], w0[2], w0[3]);
      As[0][1][sfrag][slane] = make_uint4(w1[0], w1[1], w1[2], w1[3]);
      As[0][2][sfrag][slane] = make_uint4(w2[0], w2[1], w2[2], w2[3]);
    } else {
      Bs[0][0][sfrag][slane] = make_uint4(w0[0], w0[1], w0[2], w0[3]);
      Bs[0][1][sfrag][slane] = make_uint4(w1[0], w1[1], w1[2], w1[3]);
      Bs[0][2][sfrag][slane] = make_uint4(w2[0], w2[1], w2[2], w2[3]);
    }
  }
  __syncthreads();
  for (int kb = 0; kb < 25; ++kb) {
    const int cur = kb & 1, nxt = cur ^ 1;
    if (kb < 24) {       // issue next-chunk loads early
      const int kg = (kb + 1) * 32 + skq * 8;
      if (kg < D_IN) {
        float4 v0 = *(const float4*)(srcrow + kg);
        float4 v1 = *(const float4*)(srcrow + kg + 4);
        e[0] = v0.x; e[1] = v0.y; e[2] = v0.z; e[3] = v0.w;
        e[4] = v1.x; e[5] = v1.y; e[6] = v1.z; e[7] = v1.w;
      } else {
#pragma unroll
        for (int q = 0; q < 8; ++q) e[q] = 0.0f;
      }
    }
    s16x8 A0 = __builtin_bit_cast(s16x8, As[cur][0][wm][lane]);
    s16x8 A1 = __builtin_bit_cast(s16x8, As[cur][1][wm][lane]);
    s16x8 A2 = __builtin_bit_cast(s16x8, As[cur][2][wm][lane]);
    {
      s16x8 B0 = __builtin_bit_cast(s16x8, Bs[cur][0][wn * 2][lane]);
      s16x8 B1 = __builtin_bit_cast(s16x8, Bs[cur][1][wn * 2][lane]);
      s16x8 B2 = __builtin_bit_cast(s16x8, Bs[cur][2][wn * 2][lane]);
      acc0 = __builtin_amdgcn_mfma_f32_16x16x32_bf16(A0, B0, acc0, 0, 0, 0);
      acc0 = __builtin_amdgcn_mfma_f32_16x16x32_bf16(A0, B1, acc0, 0, 0, 0);
      acc0 = __builtin_amdgcn_mfma_f32_16x16x32_bf16(A1, B0, acc0, 0, 0, 0);
      acc0 = __builtin_amdgcn_mfma_f32_16x16x32_bf16(A1, B1, acc0, 0, 0, 0);
      acc0 = __builtin_amdgcn_mfma_f32_16x16x32_bf16(A0, B2, acc0, 0, 0, 0);
      acc0 = __builtin_amdgcn_mfma_f32_16x16x32_bf16(A2, B0, acc0, 0, 0, 0);
    }
    {
      s16x8 B0 = __builtin_bit_cast(s16x8, Bs[cur][0][wn * 2 + 1][lane]);
      s16x8 B1 = __builtin_bit_cast(s16x8, Bs[cur][1][wn * 2 + 1][lane]);
      s16x8 B2 = __builtin_bit_cast(s16x8, Bs[cur][2][wn * 2 + 1][lane]);
      acc1 = __builtin_amdgcn_mfma_f32_16x16x32_bf16(A0, B0, acc1, 0, 0, 0);
      acc1 = __builtin_amdgcn_mfma_f32_16x16x32_bf16(A0, B1, acc1, 0, 0, 0);
      acc1 = __builtin_amdgcn_mfma_f32_16x16x32_bf16(A1, B0, acc1, 0, 0, 0);
      acc1 = __builtin_amdgcn_mfma_f32_16x16x32_bf16(A1, B1, acc1, 0, 0, 0);
      acc1 = __builtin_amdgcn_mfma_f32_16x16x32_bf16(A0, B2, acc1, 0, 0, 0);
      acc1 = __builtin_amdgcn_mfma_f32_16x16x32_bf16(A2, B0, acc1, 0, 0, 0);
    }
    if (kb < 24) {       // pack (waits on the early loads) + write next buf
      u32 w0[4], w1[4], w2[4];
#pragma unroll
      for (int p = 0; p < 4; ++p) packpair(e[2 * p], e[2 * p + 1], w0[p], w1[p], w2[p]);
      if (isA) {
        As[nxt][0][sfrag][slane] = make_uint4(w0[0], w0[1], w0[2], w0[3]);
        As[nxt][1][sfrag][slane] = make_uint4(w1[0], w1[1], w1[2], w1[3]);
        As[nxt][2][sfrag][slane] = make_uint4(w2[0], w2[1], w2[2], w2[3]);
      } else {
        Bs[nxt][0][sfrag][slane] = make_uint4(w0[0], w0[1], w0[2], w0[3]);
        Bs[nxt][1][sfrag][slane] = make_uint4(w1[0], w1[1], w1[2], w1[3]);
        Bs[nxt][2][sfrag][slane] = make_uint4(w2[0], w2[1], w2[2], w2[3]);
      }
    }
    __syncthreads();
  }
  const int col = lane & 15, rb = (lane >> 4) * 4;
  {
    const int gcol = nb * 64 + (wn * 2) * 16 + col;
    const float bv = b1[gcol];
#pragma unroll
    for (int r = 0; r < 4; ++r)
      cur1[(size_t)(mb * 64 + wm * 16 + rb + r) * D_H + gcol] = acc0[r] + bv;
  }
  {
    const int gcol = nb * 64 + (wn * 2 + 1) * 16 + col;
    const float bv = b1[gcol];
#pragma unroll
    for (int r = 0; r < 4; ++r)
      cur1[(size_t)(mb * 64 + wm * 16 + rb + r) * D_H + gcol] = acc1[r] + bv;
  }
}

// ---------------------------------------------------------------------------
// K2: fused temporal kernel. Branchless phase B (R11 verbatim). Phase C:
// per-block Phi/Plo COPY (b&15) + 4-deep load batching (8 independent
// loads in flight per group) to pipeline L2 latency. Same MFMA order.
// ---------------------------------------------------------------------------
__global__ __launch_bounds__(512) void k_snn4(const float* __restrict__ cur1,
                                              const u32* __restrict__ Phi,
                                              const u32* __restrict__ Plo,
                                              const float* __restrict__ b2,
                                              const float* __restrict__ beta1p,
                                              const float* __restrict__ beta2p,
                                              float* __restrict__ out) {
  __shared__ __align__(16) u32 bits[112][66];   // [t][h32], 29.6 KB
  __shared__ float c2[112][18];                 // 8 KB
  const int b = blockIdx.x;
  const int tid = threadIdx.x;
  const int wave = tid >> 6, lane = tid & 63;
  const float b1c = fminf(fmaxf(beta1p[0], 0.0f), 1.0f);
  const float b2c = fminf(fmaxf(beta2p[0], 0.0f), 1.0f);

  for (int idx = tid; idx < 12 * 66; idx += 512) bits[100 + idx / 66][idx % 66] = 0;

  // ---- phase B: branchless layer-1 recurrence (R11 verbatim) ----
  float cv[4], memv[4], spf[4];
#pragma unroll
  for (int j = 0; j < 4; ++j) {
    cv[j] = cur1[(size_t)b * D_H + j * 512 + tid];
    memv[j] = 0.0f; spf[j] = 0.0f;
  }
  for (int t = 0; t < T_STEPS; ++t) {
    u64 msk[4];
#pragma unroll
    for (int j = 0; j < 4; ++j) {
      float m = __fmul_rn(b1c, memv[j]);
      m = __fadd_rn(m, cv[j]);
      m = __fsub_rn(m, spf[j]);
      bool sp = (m > 1.0f);
      msk[j] = __ballot(sp);
      spf[j] = sp ? 1.0f : 0.0f;
      memv[j] = m;
    }
    if (lane == 0) {
      u64* rowp = (u64*)&bits[t][0];
      rowp[0 * 8 + wave] = msk[0];
      rowp[1 * 8 + wave] = msk[1];
      rowp[2 * 8 + wave] = msk[2];
      rowp[3 * 8 + wave] = msk[3];
    }
  }
  __syncthreads();

  // ---- phase C: cur2 via MFMA; replicated Phi/Plo + 4-deep load groups ----
  if (wave < 7) {
    const u32* PhiB = Phi + ((size_t)(b & (NCOPY - 1)) << 15);
    const u32* PloB = Plo + ((size_t)(b & (NCOPY - 1)) << 15);
    f32x4 acc = {0.f, 0.f, 0.f, 0.f};
    const int row0 = wave * 16 + (lane & 15);
    const int shift = (lane >> 4) * 8;
    for (int kg = 0; kg < 64; kg += 4) {
      uint4 bh[4], bl[4];
#pragma unroll
      for (int i = 0; i < 4; ++i) {
        bh[i] = *(const uint4*)(PhiB + (size_t)(kg + i) * 256 + lane * 4);
        bl[i] = *(const uint4*)(PloB + (size_t)(kg + i) * 256 + lane * 4);
      }
#pragma unroll
      for (int i = 0; i < 4; ++i) {
        u32 w8 = (bits[row0][kg + i] >> shift) & 0xFFu;
        u32 u = w8 | (w8 << 15);
        uint4 a0u;
        ((u32*)&a0u)[0] = ( u        & 0x00010001u) * 0x3F80u;
        ((u32*)&a0u)[1] = ((u >> 2)  & 0x00010001u) * 0x3F80u;
        ((u32*)&a0u)[2] = ((u >> 4)  & 0x00010001u) * 0x3F80u;
        ((u32*)&a0u)[3] = ((u >> 6)  & 0x00010001u) * 0x3F80u;
        s16x8 a   = __builtin_bit_cast(s16x8, a0u);
        s16x8 bhi = __builtin_bit_cast(s16x8, bh[i]);
        s16x8 blo = __builtin_bit_cast(s16x8, bl[i]);
        acc = __builtin_amdgcn_mfma_f32_16x16x32_bf16(a, bhi, acc, 0, 0, 0);
        acc = __builtin_amdgcn_mfma_f32_16x16x32_bf16(a, blo, acc, 0, 0, 0);
      }
    }
    const int colw = lane & 15, rbase = (lane >> 4) * 4;
#pragma unroll
    for (int r = 0; r < 4; ++r) c2[wave * 16 + rbase + r][colw] = acc[r];
  }
  __syncthreads();

  // ---- phase D: layer-2 recurrence + mean + softmax (R11 verbatim) ----
  if (tid < 16) {
    const int o = tid;
    const bool valid = (o < D_O);
    const float bb = valid ? b2[o] : 0.0f;
    float m2 = 0.0f; bool s2 = false; int cnt = 0;
    for (int t0 = 0; t0 < T_STEPS; t0 += 10) {
      float cc[10];
#pragma unroll
      for (int i = 0; i < 10; ++i) cc[i] = c2[t0 + i][o];
#pragma unroll
      for (int i = 0; i < 10; ++i) {
        float cI = __fadd_rn(cc[i], bb);
        float m = __fadd_rn(__fmul_rn(b2c, m2), cI);
        if (s2) m = __fsub_rn(m, 1.0f);
        s2 = (m > 1.0f);
        m2 = m;
        cnt += s2 ? 1 : 0;
      }
    }
    float mean = valid ? ((float)cnt / 100.0f) : -1e30f;
    float mx = mean;
#pragma unroll
    for (int i = 8; i >= 1; i >>= 1) mx = fmaxf(mx, __shfl_xor(mx, i, 16));
    float e = valid ? expf(mean - mx) : 0.0f;
    float s = e;
#pragma unroll
    for (int i = 8; i >= 1; i >>= 1) s = __fadd_rn(s, __shfl_xor(s, i, 16));
    if (valid) out[(size_t)b * D_O + o] = e / s;
  }
}

// ---------------------------------------------------------------------------
extern "C" void kernel_launch(void* const* d_in, const int* in_sizes, int n_in,
                              void* d_out, int out_size, void* d_ws, size_t ws_size,
                              hipStream_t stream) {
  const float* x     = (const float*)d_in[0];
  const float* W1    = (const float*)d_in[1];
  const float* b1    = (const float*)d_in[2];
  const float* W2    = (const float*)d_in[3];
  const float* b2    = (const float*)d_in[4];
  const float* beta1 = (const float*)d_in[5];
  const float* beta2 = (const float*)d_in[6];
  float* out = (float*)d_out;

  char* ws = (char*)d_ws;
  // layout: [0, 4M) cur1 | [4M, 6M) Phi x16 copies | [6M, 8M) Plo x16 copies
  float* cur1 = (float*)ws;
  u32*   Phi  = (u32*)(ws + 4194304);
  u32*   Plo  = (u32*)(ws + 6291456);

  hipLaunchKernelGGL(k_prep_w2, dim3(256), dim3(256), 0, stream, W2, Phi, Plo);
  hipLaunchKernelGGL(k_fgemm, dim3(256), dim3(512), 0, stream, x, W1, b1, cur1);
  hipLaunchKernelGGL(k_snn4, dim3(512), dim3(512), 0, stream,
                     cur1, Phi, Plo, b2, beta1, beta2, out);
}

// Round 13
// 66.544 us; speedup vs baseline: 1.5630x; 1.0107x over previous
//
#include <hip/hip_runtime.h>
#include <cstdint>

typedef unsigned int u32;
typedef unsigned short u16;
typedef unsigned long long u64;
typedef __attribute__((ext_vector_type(4))) float f32x4;
typedef __attribute__((ext_vector_type(8))) short s16x8;

#define D_IN   784
#define D_H    2048
#define D_O    10
#define T_STEPS 100
#define NCOPY  16

static __device__ __forceinline__ u16 f2bf_rn(float f) {
  u32 u = __float_as_uint(f);
  u32 r = u + 0x7FFFu + ((u >> 16) & 1u);
  return (u16)(r >> 16);
}
static __device__ __forceinline__ float bf2f(u16 h) {
  return __uint_as_float(((u32)h) << 16);
}

// Truncation-based triple-split of an f32 pair into three packed bf16-pair
// words. r = f - trunc16(f) is exact; dropped residual <= 2^-24 * |f|.
static __device__ __forceinline__ void packpair(float f0, float f1,
                                                u32& o0, u32& o1, u32& o2) {
  u32 u0 = __float_as_uint(f0), u1 = __float_as_uint(f1);
  o0 = (u0 >> 16) | (u1 & 0xFFFF0000u);
  float r0 = __fsub_rn(f0, __uint_as_float(u0 & 0xFFFF0000u));
  float r1 = __fsub_rn(f1, __uint_as_float(u1 & 0xFFFF0000u));
  u32 v0 = __float_as_uint(r0), v1 = __float_as_uint(r1);
  o1 = (v0 >> 16) | (v1 & 0xFFFF0000u);
  float s0 = __fsub_rn(r0, __uint_as_float(v0 & 0xFFFF0000u));
  float s1 = __fsub_rn(r1, __uint_as_float(v1 & 0xFFFF0000u));
  o2 = (__float_as_uint(s0) >> 16) | (__float_as_uint(s1) & 0xFFFF0000u);
}

// ---------------------------------------------------------------------------
// K0: W2 -> bf16 hi/lo MFMA B-fragments, replicated NCOPY times (R12 verbatim).
// ---------------------------------------------------------------------------
__global__ __launch_bounds__(256) void k_prep_w2(const float* __restrict__ W2,
                                                 u32* __restrict__ Phi,
                                                 u32* __restrict__ Plo) {
  const int blk = blockIdx.x;
  const int copy = blk >> 4;
  int t = (blk & 15) * 256 + threadIdx.x;   // 0..4095
  int kb = t >> 6, l = t & 63;
  int o = l & 15;
  int kbase = kb * 32 + ((l >> 4) << 3);
  u32 hw[4], lw[4];
#pragma unroll
  for (int p = 0; p < 4; ++p) {
    u32 hp = 0, lp = 0;
#pragma unroll
    for (int q = 0; q < 2; ++q) {
      float f = (o < D_O) ? W2[o * D_H + kbase + 2 * p + q] : 0.0f;
      u16 h = f2bf_rn(f);
      float rr = __fsub_rn(f, bf2f(h));
      u16 lo = f2bf_rn(rr);
      hp |= ((u32)h) << (16 * q);
      lp |= ((u32)lo) << (16 * q);
    }
    hw[p] = hp; lw[p] = lp;
  }
  int base = (copy << 15) + (kb * 64 + l) * 4;
#pragma unroll
  for (int p = 0; p < 4; ++p) { Phi[base + p] = hw[p]; Plo[base + p] = lw[p]; }
}

// ---------------------------------------------------------------------------
// K1: FUSED split+GEMM, double-buffered (R12 structure) with VGPR headroom:
// __launch_bounds__(512, 2) -> 256-VGPR budget so the e[]-prefetch and LDS
// pipeline are NOT flattened by the register allocator.
// ---------------------------------------------------------------------------
__global__ __launch_bounds__(512, 2) void k_fgemm(const float* __restrict__ x,
                                                  const float* __restrict__ W1,
                                                  const float* __restrict__ b1,
                                                  float* __restrict__ cur1) {
  __shared__ uint4 As[2][3][4][64];   // 24 KB
  __shared__ uint4 Bs[2][3][4][64];   // 24 KB
  const int tid = threadIdx.x, wave = tid >> 6, lane = tid & 63;
  const int id = blockIdx.x;
  const int sub = id >> 3;                  // 0..31
  const int mb = sub >> 2;                  // 0..7   (batch-row tile)
  const int nb = (id & 7) * 4 + (sub & 3);  // 0..31  (hidden-col tile)
  const int wm = wave >> 1, wn = wave & 1;
  const int st = tid & 255;
  const int srow = st >> 2, skq = st & 3;
  const int sfrag = srow >> 4;
  const int slane = skq * 16 + (srow & 15);
  const bool isA = (tid < 256);
  const float* srcrow = isA ? (x  + (size_t)(mb * 64 + srow) * D_IN)
                            : (W1 + (size_t)(nb * 64 + srow) * D_IN);
  f32x4 acc0 = {0.f, 0.f, 0.f, 0.f}, acc1 = {0.f, 0.f, 0.f, 0.f};
  float e[8];
  {
    const int kg = skq * 8;
    float4 v0 = *(const float4*)(srcrow + kg);
    float4 v1 = *(const float4*)(srcrow + kg + 4);
    e[0] = v0.x; e[1] = v0.y; e[2] = v0.z; e[3] = v0.w;
    e[4] = v1.x; e[5] = v1.y; e[6] = v1.z; e[7] = v1.w;
  }
  {  // prologue: pack kb=0 into buffer 0
    u32 w0[4], w1[4], w2[4];
#pragma unroll
    for (int p = 0; p < 4; ++p) packpair(e[2 * p], e[2 * p + 1], w0[p], w1[p], w2[p]);
    if (isA) {
      As[0][0][sfrag][slane] = make_uint4(w0[0], w0[1], w0[2], w0[3]);
      As[0][1][sfrag][slane] = make_uint4(w1[0], w1[1], w1[2], w1[3]);
      As[0][2][sfrag][slane] = make_uint4(w2[0], w2[1], w2[2], w2[3]);
    } else {
      Bs[0][0][sfrag][slane] = make_uint4(w0[0], w0[1], w0[2], w0[3]);
      Bs[0][1][sfrag][slane] = make_uint4(w1[0], w1[1], w1[2], w1[3]);
      Bs[0][2][sfrag][slane] = make_uint4(w2[0], w2[1], w2[2], w2[3]);
    }
  }
  __syncthreads();
  for (int kb = 0; kb < 25; ++kb) {
    const int cur = kb & 1, nxt = cur ^ 1;
    if (kb < 24) {       // issue next-chunk loads early
      const int kg = (kb + 1) * 32 + skq * 8;
      if (kg < D_IN) {
        float4 v0 = *(const float4*)(srcrow + kg);
        float4 v1 = *(const float4*)(srcrow + kg + 4);
        e[0] = v0.x; e[1] = v0.y; e[2] = v0.z; e[3] = v0.w;
        e[4] = v1.x; e[5] = v1.y; e[6] = v1.z; e[7] = v1.w;
      } else {
#pragma unroll
        for (int q = 0; q < 8; ++q) e[q] = 0.0f;
      }
    }
    s16x8 A0 = __builtin_bit_cast(s16x8, As[cur][0][wm][lane]);
    s16x8 A1 = __builtin_bit_cast(s16x8, As[cur][1][wm][lane]);
    s16x8 A2 = __builtin_bit_cast(s16x8, As[cur][2][wm][lane]);
    {
      s16x8 B0 = __builtin_bit_cast(s16x8, Bs[cur][0][wn * 2][lane]);
      s16x8 B1 = __builtin_bit_cast(s16x8, Bs[cur][1][wn * 2][lane]);
      s16x8 B2 = __builtin_bit_cast(s16x8, Bs[cur][2][wn * 2][lane]);
      acc0 = __builtin_amdgcn_mfma_f32_16x16x32_bf16(A0, B0, acc0, 0, 0, 0);
      acc0 = __builtin_amdgcn_mfma_f32_16x16x32_bf16(A0, B1, acc0, 0, 0, 0);
      acc0 = __builtin_amdgcn_mfma_f32_16x16x32_bf16(A1, B0, acc0, 0, 0, 0);
      acc0 = __builtin_amdgcn_mfma_f32_16x16x32_bf16(A1, B1, acc0, 0, 0, 0);
      acc0 = __builtin_amdgcn_mfma_f32_16x16x32_bf16(A0, B2, acc0, 0, 0, 0);
      acc0 = __builtin_amdgcn_mfma_f32_16x16x32_bf16(A2, B0, acc0, 0, 0, 0);
    }
    {
      s16x8 B0 = __builtin_bit_cast(s16x8, Bs[cur][0][wn * 2 + 1][lane]);
      s16x8 B1 = __builtin_bit_cast(s16x8, Bs[cur][1][wn * 2 + 1][lane]);
      s16x8 B2 = __builtin_bit_cast(s16x8, Bs[cur][2][wn * 2 + 1][lane]);
      acc1 = __builtin_amdgcn_mfma_f32_16x16x32_bf16(A0, B0, acc1, 0, 0, 0);
      acc1 = __builtin_amdgcn_mfma_f32_16x16x32_bf16(A0, B1, acc1, 0, 0, 0);
      acc1 = __builtin_amdgcn_mfma_f32_16x16x32_bf16(A1, B0, acc1, 0, 0, 0);
      acc1 = __builtin_amdgcn_mfma_f32_16x16x32_bf16(A1, B1, acc1, 0, 0, 0);
      acc1 = __builtin_amdgcn_mfma_f32_16x16x32_bf16(A0, B2, acc1, 0, 0, 0);
      acc1 = __builtin_amdgcn_mfma_f32_16x16x32_bf16(A2, B0, acc1, 0, 0, 0);
    }
    if (kb < 24) {       // pack (waits on the early loads) + write next buf
      u32 w0[4], w1[4], w2[4];
#pragma unroll
      for (int p = 0; p < 4; ++p) packpair(e[2 * p], e[2 * p + 1], w0[p], w1[p], w2[p]);
      if (isA) {
        As[nxt][0][sfrag][slane] = make_uint4(w0[0], w0[1], w0[2], w0[3]);
        As[nxt][1][sfrag][slane] = make_uint4(w1[0], w1[1], w1[2], w1[3]);
        As[nxt][2][sfrag][slane] = make_uint4(w2[0], w2[1], w2[2], w2[3]);
      } else {
        Bs[nxt][0][sfrag][slane] = make_uint4(w0[0], w0[1], w0[2], w0[3]);
        Bs[nxt][1][sfrag][slane] = make_uint4(w1[0], w1[1], w1[2], w1[3]);
        Bs[nxt][2][sfrag][slane] = make_uint4(w2[0], w2[1], w2[2], w2[3]);
      }
    }
    __syncthreads();
  }
  const int col = lane & 15, rb = (lane >> 4) * 4;
  {
    const int gcol = nb * 64 + (wn * 2) * 16 + col;
    const float bv = b1[gcol];
#pragma unroll
    for (int r = 0; r < 4; ++r)
      cur1[(size_t)(mb * 64 + wm * 16 + rb + r) * D_H + gcol] = acc0[r] + bv;
  }
  {
    const int gcol = nb * 64 + (wn * 2 + 1) * 16 + col;
    const float bv = b1[gcol];
#pragma unroll
    for (int r = 0; r < 4; ++r)
      cur1[(size_t)(mb * 64 + wm * 16 + rb + r) * D_H + gcol] = acc1[r] + bv;
  }
}

// ---------------------------------------------------------------------------
// K2: fused temporal kernel. Branchless phase B (R11 verbatim). Phase C:
// FULLY-UNROLLED 2-deep software-pipelined load groups (compile-time buffer
// indices; 8 uint4 loads structurally live across each MFMA block) with
// __launch_bounds__(512, 4) -> 128-VGPR budget so the pipeline survives
// register allocation (R12's VGPR_Count=36 flattened it).
// ---------------------------------------------------------------------------
__global__ __launch_bounds__(512, 4) void k_snn5(const float* __restrict__ cur1,
                                                 const u32* __restrict__ Phi,
                                                 const u32* __restrict__ Plo,
                                                 const float* __restrict__ b2,
                                                 const float* __restrict__ beta1p,
                                                 const float* __restrict__ beta2p,
                                                 float* __restrict__ out) {
  __shared__ __align__(16) u32 bits[112][66];   // [t][h32], 29.6 KB
  __shared__ float c2[112][18];                 // 8 KB
  const int b = blockIdx.x;
  const int tid = threadIdx.x;
  const int wave = tid >> 6, lane = tid & 63;
  const float b1c = fminf(fmaxf(beta1p[0], 0.0f), 1.0f);
  const float b2c = fminf(fmaxf(beta2p[0], 0.0f), 1.0f);

  for (int idx = tid; idx < 12 * 66; idx += 512) bits[100 + idx / 66][idx % 66] = 0;

  // ---- phase B: branchless layer-1 recurrence (R11 verbatim) ----
  float cv[4], memv[4], spf[4];
#pragma unroll
  for (int j = 0; j < 4; ++j) {
    cv[j] = cur1[(size_t)b * D_H + j * 512 + tid];
    memv[j] = 0.0f; spf[j] = 0.0f;
  }
  for (int t = 0; t < T_STEPS; ++t) {
    u64 msk[4];
#pragma unroll
    for (int j = 0; j < 4; ++j) {
      float m = __fmul_rn(b1c, memv[j]);
      m = __fadd_rn(m, cv[j]);
      m = __fsub_rn(m, spf[j]);
      bool sp = (m > 1.0f);
      msk[j] = __ballot(sp);
      spf[j] = sp ? 1.0f : 0.0f;
      memv[j] = m;
    }
    if (lane == 0) {
      u64* rowp = (u64*)&bits[t][0];
      rowp[0 * 8 + wave] = msk[0];
      rowp[1 * 8 + wave] = msk[1];
      rowp[2 * 8 + wave] = msk[2];
      rowp[3 * 8 + wave] = msk[3];
    }
  }
  __syncthreads();

  // ---- phase C: cur2 via MFMA, 2-deep pipelined load groups ----
  if (wave < 7) {
    const u32* PhiB = Phi + ((size_t)(b & (NCOPY - 1)) << 15) + lane * 4;
    const u32* PloB = Plo + ((size_t)(b & (NCOPY - 1)) << 15) + lane * 4;
    f32x4 acc = {0.f, 0.f, 0.f, 0.f};
    const int row0 = wave * 16 + (lane & 15);
    const int shift = (lane >> 4) * 8;
    uint4 bhA[4], blA[4], bhB[4], blB[4];
#pragma unroll
    for (int i = 0; i < 4; ++i) {
      bhA[i] = *(const uint4*)(PhiB + (size_t)i * 256);
      blA[i] = *(const uint4*)(PloB + (size_t)i * 256);
    }
#pragma unroll
    for (int g = 0; g < 16; ++g) {
      // issue next group's 8 loads before consuming current (compile-time sel)
      if (g < 15) {
        if ((g & 1) == 0) {
#pragma unroll
          for (int i = 0; i < 4; ++i) {
            bhB[i] = *(const uint4*)(PhiB + (size_t)((g + 1) * 4 + i) * 256);
            blB[i] = *(const uint4*)(PloB + (size_t)((g + 1) * 4 + i) * 256);
          }
        } else {
#pragma unroll
          for (int i = 0; i < 4; ++i) {
            bhA[i] = *(const uint4*)(PhiB + (size_t)((g + 1) * 4 + i) * 256);
            blA[i] = *(const uint4*)(PloB + (size_t)((g + 1) * 4 + i) * 256);
          }
        }
      }
#pragma unroll
      for (int i = 0; i < 4; ++i) {
        u32 w8 = (bits[row0][g * 4 + i] >> shift) & 0xFFu;
        u32 u = w8 | (w8 << 15);
        uint4 a0u;
        ((u32*)&a0u)[0] = ( u        & 0x00010001u) * 0x3F80u;
        ((u32*)&a0u)[1] = ((u >> 2)  & 0x00010001u) * 0x3F80u;
        ((u32*)&a0u)[2] = ((u >> 4)  & 0x00010001u) * 0x3F80u;
        ((u32*)&a0u)[3] = ((u >> 6)  & 0x00010001u) * 0x3F80u;
        s16x8 a = __builtin_bit_cast(s16x8, a0u);
        s16x8 bhi, blo;
        if ((g & 1) == 0) {
          bhi = __builtin_bit_cast(s16x8, bhA[i]);
          blo = __builtin_bit_cast(s16x8, blA[i]);
        } else {
          bhi = __builtin_bit_cast(s16x8, bhB[i]);
          blo = __builtin_bit_cast(s16x8, blB[i]);
        }
        acc = __builtin_amdgcn_mfma_f32_16x16x32_bf16(a, bhi, acc, 0, 0, 0);
        acc = __builtin_amdgcn_mfma_f32_16x16x32_bf16(a, blo, acc, 0, 0, 0);
      }
    }
    const int colw = lane & 15, rbase = (lane >> 4) * 4;
#pragma unroll
    for (int r = 0; r < 4; ++r) c2[wave * 16 + rbase + r][colw] = acc[r];
  }
  __syncthreads();

  // ---- phase D: layer-2 recurrence + mean + softmax (R11 verbatim) ----
  if (tid < 16) {
    const int o = tid;
    const bool valid = (o < D_O);
    const float bb = valid ? b2[o] : 0.0f;
    float m2 = 0.0f; bool s2 = false; int cnt = 0;
    for (int t0 = 0; t0 < T_STEPS; t0 += 10) {
      float cc[10];
#pragma unroll
      for (int i = 0; i < 10; ++i) cc[i] = c2[t0 + i][o];
#pragma unroll
      for (int i = 0; i < 10; ++i) {
        float cI = __fadd_rn(cc[i], bb);
        float m = __fadd_rn(__fmul_rn(b2c, m2), cI);
        if (s2) m = __fsub_rn(m, 1.0f);
        s2 = (m > 1.0f);
        m2 = m;
        cnt += s2 ? 1 : 0;
      }
    }
    float mean = valid ? ((float)cnt / 100.0f) : -1e30f;
    float mx = mean;
#pragma unroll
    for (int i = 8; i >= 1; i >>= 1) mx = fmaxf(mx, __shfl_xor(mx, i, 16));
    float e = valid ? expf(mean - mx) : 0.0f;
    float s = e;
#pragma unroll
    for (int i = 8; i >= 1; i >>= 1) s = __fadd_rn(s, __shfl_xor(s, i, 16));
    if (valid) out[(size_t)b * D_O + o] = e / s;
  }
}

// ---------------------------------------------------------------------------
extern "C" void kernel_launch(void* const* d_in, const int* in_sizes, int n_in,
                              void* d_out, int out_size, void* d_ws, size_t ws_size,
                              hipStream_t stream) {
  const float* x     = (const float*)d_in[0];
  const float* W1    = (const float*)d_in[1];
  const float* b1    = (const float*)d_in[2];
  const float* W2    = (const float*)d_in[3];
  const float* b2    = (const float*)d_in[4];
  const float* beta1 = (const float*)d_in[5];
  const float* beta2 = (const float*)d_in[6];
  float* out = (float*)d_out;

  char* ws = (char*)d_ws;
  // layout: [0, 4M) cur1 | [4M, 6M) Phi x16 copies | [6M, 8M) Plo x16 copies
  float* cur1 = (float*)ws;
  u32*   Phi  = (u32*)(ws + 4194304);
  u32*   Plo  = (u32*)(ws + 6291456);

  hipLaunchKernelGGL(k_prep_w2, dim3(256), dim3(256), 0, stream, W2, Phi, Plo);
  hipLaunchKernelGGL(k_fgemm, dim3(256), dim3(512), 0, stream, x, W1, b1, cur1);
  hipLaunchKernelGGL(k_snn5, dim3(512), dim3(512), 0, stream,
                     cur1, Phi, Plo, b2, beta1, beta2, out);
}